// Round 1
// baseline (656.995 us; speedup 1.0000x reference)
//
#include <hip/hip_runtime.h>

#define N_NODES 50000
#define N_EDGES 800000

// ---------------------------------------------------------------------------
// Graph build: in-degree count -> dinv -> exclusive scan -> CSR fill
// ---------------------------------------------------------------------------

__global__ void count_kernel(const int* __restrict__ ei, int* __restrict__ deg, int E) {
    int e = blockIdx.x * blockDim.x + threadIdx.x;
    if (e < E) atomicAdd(&deg[ei[E + e]], 1);   // col = destination
}

__global__ void dinv_kernel(const int* __restrict__ deg, float* __restrict__ dinv, int n) {
    int i = blockIdx.x * blockDim.x + threadIdx.x;
    if (i < n) dinv[i] = rsqrtf((float)(deg[i] + 1));   // +1 self loop
}

// Single-block exclusive scan of deg[0..n) -> offsets, cursor. n=50000, 1024 thr.
__global__ void scan_kernel(const int* __restrict__ deg, int* __restrict__ offsets,
                            int* __restrict__ cursor, int n, int total) {
    __shared__ int sums[1024];
    int tid = threadIdx.x;
    int per = (n + 1023) / 1024;
    int start = tid * per;
    int end = start + per; if (end > n) end = n;
    int s = 0;
    for (int i = start; i < end; ++i) s += deg[i];
    sums[tid] = s;
    __syncthreads();
    // Hillis-Steele inclusive scan over 1024 partials
    for (int off = 1; off < 1024; off <<= 1) {
        int v = (tid >= off) ? sums[tid - off] : 0;
        __syncthreads();
        sums[tid] += v;
        __syncthreads();
    }
    int base = (tid > 0) ? sums[tid - 1] : 0;   // exclusive prefix of this strip
    for (int i = start; i < end; ++i) {
        offsets[i] = base;
        cursor[i]  = base;
        base += deg[i];
    }
    if (tid == 1023) offsets[n] = total;
}

__global__ void fill_kernel(const int* __restrict__ ei, int* __restrict__ cursor,
                            int* __restrict__ csr_src, int E) {
    int e = blockIdx.x * blockDim.x + threadIdx.x;
    if (e < E) {
        int c = ei[E + e];
        int pos = atomicAdd(&cursor[c], 1);
        csr_src[pos] = ei[e];   // row = source
    }
}

// ---------------------------------------------------------------------------
// GEMM: h[i][j] = (x[i,:] @ W[:,j]) * dinv[i].   FI = 128 always.
// Block: 256 threads. Thread tile: 4 rows x 16 cols. W staged in LDS.
// ---------------------------------------------------------------------------

template<int FO>
__global__ __launch_bounds__(256) void gemm_scale_kernel(
        const float* __restrict__ x, const float* __restrict__ W,
        const float* __restrict__ dinv, float* __restrict__ h, int n) {
    constexpr int TC   = FO / 16;      // thread-cols per row group (8 or 4)
    constexpr int TR   = 256 / TC;     // row groups (32 or 64)
    constexpr int ROWS = TR * 4;       // rows per block (128 or 256)

    __shared__ float w_lds[128 * FO];  // 64 KB (FO=128) / 32 KB (FO=64)
    int tid = threadIdx.x;
    #pragma unroll 4
    for (int idx = tid * 4; idx < 128 * FO; idx += 1024)
        *(float4*)&w_lds[idx] = *(const float4*)&W[idx];
    __syncthreads();

    int tc = tid % TC, tr = tid / TC;
    int j0   = tc * 16;
    int row0 = blockIdx.x * ROWS + tr * 4;

    float acc[4][16];
    #pragma unroll
    for (int r = 0; r < 4; ++r)
        #pragma unroll
        for (int c = 0; c < 16; ++c) acc[r][c] = 0.0f;

    for (int kk = 0; kk < 128; kk += 4) {
        float xbuf[4][4];
        #pragma unroll
        for (int r = 0; r < 4; ++r) {
            int row = row0 + r;
            float4 v;
            if (row < n) v = *(const float4*)&x[(size_t)row * 128 + kk];
            else         v = make_float4(0.f, 0.f, 0.f, 0.f);
            xbuf[r][0] = v.x; xbuf[r][1] = v.y; xbuf[r][2] = v.z; xbuf[r][3] = v.w;
        }
        #pragma unroll
        for (int dk = 0; dk < 4; ++dk) {
            const float* wr = &w_lds[(kk + dk) * FO + j0];
            float w[16];
            #pragma unroll
            for (int q = 0; q < 4; ++q) {
                float4 wv = *(const float4*)&wr[q * 4];
                w[q*4+0] = wv.x; w[q*4+1] = wv.y; w[q*4+2] = wv.z; w[q*4+3] = wv.w;
            }
            #pragma unroll
            for (int r = 0; r < 4; ++r) {
                float xs = xbuf[r][dk];
                #pragma unroll
                for (int c = 0; c < 16; ++c)
                    acc[r][c] = fmaf(xs, w[c], acc[r][c]);
            }
        }
    }

    #pragma unroll
    for (int r = 0; r < 4; ++r) {
        int row = row0 + r;
        if (row < n) {
            float d = dinv[row];
            #pragma unroll
            for (int q = 0; q < 4; ++q) {
                float4 o;
                o.x = acc[r][q*4+0] * d;
                o.y = acc[r][q*4+1] * d;
                o.z = acc[r][q*4+2] * d;
                o.w = acc[r][q*4+3] * d;
                *(float4*)&h[(size_t)row * FO + j0 + q * 4] = o;
            }
        }
    }
}

// ---------------------------------------------------------------------------
// Aggregation: out[c][j] = dinv[c] * (h[c][j] + sum_{src in in(c)} h[src][j]) + b[j]
// One node per block, one feature per thread. h is already scaled by dinv[src].
// ---------------------------------------------------------------------------

template<int FO, bool RELU>
__global__ void agg_kernel(const float* __restrict__ h, const int* __restrict__ offsets,
                           const int* __restrict__ csr_src, const float* __restrict__ dinv,
                           const float* __restrict__ bias, float* __restrict__ out) {
    int c = blockIdx.x;
    int j = threadIdx.x;
    float acc = h[(size_t)c * FO + j];   // self loop
    int s = offsets[c], e = offsets[c + 1];
    int i = s;
    for (; i + 3 < e; i += 4) {
        int s0 = csr_src[i], s1 = csr_src[i+1], s2 = csr_src[i+2], s3 = csr_src[i+3];
        float a0 = h[(size_t)s0 * FO + j];
        float a1 = h[(size_t)s1 * FO + j];
        float a2 = h[(size_t)s2 * FO + j];
        float a3 = h[(size_t)s3 * FO + j];
        acc += a0; acc += a1; acc += a2; acc += a3;
    }
    for (; i < e; ++i) {
        int src = csr_src[i];
        acc += h[(size_t)src * FO + j];
    }
    float v = fmaf(acc, dinv[c], bias[j]);
    if (RELU) v = fmaxf(v, 0.0f);
    out[(size_t)c * FO + j] = v;
}

// ---------------------------------------------------------------------------

extern "C" void kernel_launch(void* const* d_in, const int* in_sizes, int n_in,
                              void* d_out, int out_size, void* d_ws, size_t ws_size,
                              hipStream_t stream) {
    const float* x  = (const float*)d_in[0];
    const int*   ei = (const int*)  d_in[1];   // [2, E] row-major, int32
    const float* W1 = (const float*)d_in[2];
    const float* b1 = (const float*)d_in[3];
    const float* W2 = (const float*)d_in[4];
    const float* b2 = (const float*)d_in[5];
    const float* W3 = (const float*)d_in[6];
    const float* b3 = (const float*)d_in[7];
    const float* W4 = (const float*)d_in[8];
    const float* b4 = (const float*)d_in[9];

    const int N = N_NODES, E = N_EDGES;

    // workspace carve (256-B aligned)
    char* p = (char*)d_ws;
    auto carve = [&](size_t bytes) {
        char* q = p;
        p += (bytes + 255) & ~(size_t)255;
        return (void*)q;
    };
    int*   deg     = (int*)  carve((size_t)N * 4);
    int*   offsets = (int*)  carve((size_t)(N + 1) * 4);
    int*   cursor  = (int*)  carve((size_t)N * 4);
    int*   csr_src = (int*)  carve((size_t)E * 4);
    float* dinv    = (float*)carve((size_t)N * 4);
    float* A       = (float*)carve((size_t)N * 128 * 4);
    float* B       = (float*)carve((size_t)N * 128 * 4);

    // ---- graph build ----
    hipMemsetAsync(deg, 0, (size_t)N * 4, stream);
    count_kernel<<<(E + 255) / 256, 256, 0, stream>>>(ei, deg, E);
    dinv_kernel<<<(N + 255) / 256, 256, 0, stream>>>(deg, dinv, N);
    scan_kernel<<<1, 1024, 0, stream>>>(deg, offsets, cursor, N, E);
    fill_kernel<<<(E + 255) / 256, 256, 0, stream>>>(ei, cursor, csr_src, E);

    // ---- layers ----
    const int gemm128_grid = (N + 127) / 128;
    const int gemm64_grid  = (N + 255) / 256;

    // L1: x -> A -> B (relu)
    gemm_scale_kernel<128><<<gemm128_grid, 256, 0, stream>>>(x, W1, dinv, A, N);
    agg_kernel<128, true><<<N, 128, 0, stream>>>(A, offsets, csr_src, dinv, b1, B);
    // L2: B -> A -> B (relu)
    gemm_scale_kernel<128><<<gemm128_grid, 256, 0, stream>>>(B, W2, dinv, A, N);
    agg_kernel<128, true><<<N, 128, 0, stream>>>(A, offsets, csr_src, dinv, b2, B);
    // L3: B -> A -> B (relu)
    gemm_scale_kernel<128><<<gemm128_grid, 256, 0, stream>>>(B, W3, dinv, A, N);
    agg_kernel<128, true><<<N, 128, 0, stream>>>(A, offsets, csr_src, dinv, b3, B);
    // L4: B -> A -> d_out (no relu)
    gemm_scale_kernel<64><<<gemm64_grid, 256, 0, stream>>>(B, W4, dinv, A, N);
    agg_kernel<64, false><<<N, 64, 0, stream>>>(A, offsets, csr_src, dinv, b4, (float*)d_out);
}

// Round 2
// 580.567 us; speedup vs baseline: 1.1316x; 1.1316x over previous
//
#include <hip/hip_runtime.h>

#define N_NODES 50000
#define N_EDGES 800000

// ---------------------------------------------------------------------------
// Graph build: in-degree count -> dinv -> 3-phase exclusive scan -> CSR fill
// ---------------------------------------------------------------------------

__global__ void count_kernel(const int* __restrict__ ei, int* __restrict__ deg, int E) {
    int e = blockIdx.x * blockDim.x + threadIdx.x;
    if (e < E) atomicAdd(&deg[ei[E + e]], 1);   // col = destination
}

__global__ void dinv_kernel(const int* __restrict__ deg, float* __restrict__ dinv, int n) {
    int i = blockIdx.x * blockDim.x + threadIdx.x;
    if (i < n) dinv[i] = rsqrtf((float)(deg[i] + 1));   // +1 self loop
}

// Phase A: per-block (1024-element chunk) sums. 256 thr, 4 elems/thr.
__global__ __launch_bounds__(256) void scan_blocksum(const int* __restrict__ deg,
                                                     int* __restrict__ blocksum, int n) {
    int tid = threadIdx.x;
    int i0 = blockIdx.x * 1024 + tid * 4;
    int4 d = make_int4(0, 0, 0, 0);
    if (i0 + 3 < n) d = *(const int4*)&deg[i0];
    else {
        if (i0 < n)     d.x = deg[i0];
        if (i0 + 1 < n) d.y = deg[i0 + 1];
        if (i0 + 2 < n) d.z = deg[i0 + 2];
        if (i0 + 3 < n) d.w = deg[i0 + 3];
    }
    int s = d.x + d.y + d.z + d.w;
    #pragma unroll
    for (int off = 1; off < 64; off <<= 1) s += __shfl_xor(s, off);
    __shared__ int ws[4];
    if ((tid & 63) == 0) ws[tid >> 6] = s;
    __syncthreads();
    if (tid == 0) blocksum[blockIdx.x] = ws[0] + ws[1] + ws[2] + ws[3];
}

// Phase B: single wave scans <=64 block sums -> exclusive block offsets.
__global__ void scan_blockoff(const int* __restrict__ blocksum, int* __restrict__ blockoff,
                              int nb, int* __restrict__ offsets, int n, int total) {
    int lane = threadIdx.x;
    int v = (lane < nb) ? blocksum[lane] : 0;
    int orig = v;
    #pragma unroll
    for (int off = 1; off < 64; off <<= 1) {
        int t = __shfl_up(v, off);
        if (lane >= off) v += t;
    }
    if (lane < nb) blockoff[lane] = v - orig;
    if (lane == 0) offsets[n] = total;
}

// Phase C: per-block exclusive scan + add block offset -> offsets & cursor.
__global__ __launch_bounds__(256) void scan_fill(const int* __restrict__ deg,
                                                 const int* __restrict__ blockoff,
                                                 int* __restrict__ offsets,
                                                 int* __restrict__ cursor, int n) {
    int tid = threadIdx.x;
    int i0 = blockIdx.x * 1024 + tid * 4;
    int4 d = make_int4(0, 0, 0, 0);
    if (i0 + 3 < n) d = *(const int4*)&deg[i0];
    else {
        if (i0 < n)     d.x = deg[i0];
        if (i0 + 1 < n) d.y = deg[i0 + 1];
        if (i0 + 2 < n) d.z = deg[i0 + 2];
        if (i0 + 3 < n) d.w = deg[i0 + 3];
    }
    int ts = d.x + d.y + d.z + d.w;
    __shared__ int sbuf[256];
    sbuf[tid] = ts;
    __syncthreads();
    #pragma unroll
    for (int off = 1; off < 256; off <<= 1) {
        int t = (tid >= off) ? sbuf[tid - off] : 0;
        __syncthreads();
        sbuf[tid] += t;
        __syncthreads();
    }
    int base = blockoff[blockIdx.x] + (sbuf[tid] - ts);   // exclusive prefix
    int o0 = base, o1 = o0 + d.x, o2 = o1 + d.y, o3 = o2 + d.z;
    if (i0 + 3 < n) {
        *(int4*)&offsets[i0] = make_int4(o0, o1, o2, o3);
        *(int4*)&cursor[i0]  = make_int4(o0, o1, o2, o3);
    } else {
        if (i0 < n)     { offsets[i0]     = o0; cursor[i0]     = o0; }
        if (i0 + 1 < n) { offsets[i0 + 1] = o1; cursor[i0 + 1] = o1; }
        if (i0 + 2 < n) { offsets[i0 + 2] = o2; cursor[i0 + 2] = o2; }
        if (i0 + 3 < n) { offsets[i0 + 3] = o3; cursor[i0 + 3] = o3; }
    }
}

__global__ void fill_kernel(const int* __restrict__ ei, int* __restrict__ cursor,
                            int* __restrict__ csr_src, int E) {
    int e = blockIdx.x * blockDim.x + threadIdx.x;
    if (e < E) {
        int c = ei[E + e];
        int pos = atomicAdd(&cursor[c], 1);
        csr_src[pos] = ei[e];   // row = source
    }
}

// ---------------------------------------------------------------------------
// GEMM: h[i][j] = (x[i,:] @ W[:,j]) * dinv[i].   FI = 128 always.
// ---------------------------------------------------------------------------

template<int FO>
__global__ __launch_bounds__(256) void gemm_scale_kernel(
        const float* __restrict__ x, const float* __restrict__ W,
        const float* __restrict__ dinv, float* __restrict__ h, int n) {
    constexpr int TC   = FO / 16;      // thread-cols per row group (8 or 4)
    constexpr int TR   = 256 / TC;     // row groups (32 or 64)
    constexpr int ROWS = TR * 4;       // rows per block (128 or 256)

    __shared__ float w_lds[128 * FO];
    int tid = threadIdx.x;
    #pragma unroll 4
    for (int idx = tid * 4; idx < 128 * FO; idx += 1024)
        *(float4*)&w_lds[idx] = *(const float4*)&W[idx];
    __syncthreads();

    int tc = tid % TC, tr = tid / TC;
    int j0   = tc * 16;
    int row0 = blockIdx.x * ROWS + tr * 4;

    float acc[4][16];
    #pragma unroll
    for (int r = 0; r < 4; ++r)
        #pragma unroll
        for (int c = 0; c < 16; ++c) acc[r][c] = 0.0f;

    for (int kk = 0; kk < 128; kk += 4) {
        float xbuf[4][4];
        #pragma unroll
        for (int r = 0; r < 4; ++r) {
            int row = row0 + r;
            float4 v;
            if (row < n) v = *(const float4*)&x[(size_t)row * 128 + kk];
            else         v = make_float4(0.f, 0.f, 0.f, 0.f);
            xbuf[r][0] = v.x; xbuf[r][1] = v.y; xbuf[r][2] = v.z; xbuf[r][3] = v.w;
        }
        #pragma unroll
        for (int dk = 0; dk < 4; ++dk) {
            const float* wr = &w_lds[(kk + dk) * FO + j0];
            float w[16];
            #pragma unroll
            for (int q = 0; q < 4; ++q) {
                float4 wv = *(const float4*)&wr[q * 4];
                w[q*4+0] = wv.x; w[q*4+1] = wv.y; w[q*4+2] = wv.z; w[q*4+3] = wv.w;
            }
            #pragma unroll
            for (int r = 0; r < 4; ++r) {
                float xs = xbuf[r][dk];
                #pragma unroll
                for (int c = 0; c < 16; ++c)
                    acc[r][c] = fmaf(xs, w[c], acc[r][c]);
            }
        }
    }

    #pragma unroll
    for (int r = 0; r < 4; ++r) {
        int row = row0 + r;
        if (row < n) {
            float d = dinv[row];
            #pragma unroll
            for (int q = 0; q < 4; ++q) {
                float4 o;
                o.x = acc[r][q*4+0] * d;
                o.y = acc[r][q*4+1] * d;
                o.z = acc[r][q*4+2] * d;
                o.w = acc[r][q*4+3] * d;
                *(float4*)&h[(size_t)row * FO + j0 + q * 4] = o;
            }
        }
    }
}

// ---------------------------------------------------------------------------
// Aggregation: out[c][j] = dinv[c] * (h[c][j] + sum_{src in in(c)} h[src][j]) + b[j]
// One 64-lane wave per node; lane handles float2 (FO=128) or float (FO=64).
// 4 nodes per 256-thread block.
// ---------------------------------------------------------------------------

template<bool RELU>
__global__ __launch_bounds__(256) void agg128_kernel(
        const float* __restrict__ h, const int* __restrict__ offsets,
        const int* __restrict__ csr_src, const float* __restrict__ dinv,
        const float* __restrict__ bias, float* __restrict__ out, int n) {
    int lane = threadIdx.x & 63;
    int c = (blockIdx.x << 2) + (threadIdx.x >> 6);
    if (c >= n) return;
    const float2* h2 = (const float2*)h;
    size_t cbase = (size_t)c * 64 + lane;
    float2 acc = h2[cbase];   // self loop (already scaled by dinv[c])
    int s = offsets[c], e = offsets[c + 1];
    int i = s;
    for (; i + 3 < e; i += 4) {
        int s0 = csr_src[i], s1 = csr_src[i+1], s2 = csr_src[i+2], s3 = csr_src[i+3];
        float2 a0 = h2[(size_t)s0 * 64 + lane];
        float2 a1 = h2[(size_t)s1 * 64 + lane];
        float2 a2 = h2[(size_t)s2 * 64 + lane];
        float2 a3 = h2[(size_t)s3 * 64 + lane];
        acc.x += a0.x + a1.x; acc.y += a0.y + a1.y;
        acc.x += a2.x + a3.x; acc.y += a2.y + a3.y;
    }
    for (; i < e; ++i) {
        float2 a = h2[(size_t)csr_src[i] * 64 + lane];
        acc.x += a.x; acc.y += a.y;
    }
    float dc = dinv[c];
    float2 bb = ((const float2*)bias)[lane];
    float vx = fmaf(acc.x, dc, bb.x);
    float vy = fmaf(acc.y, dc, bb.y);
    if (RELU) { vx = fmaxf(vx, 0.0f); vy = fmaxf(vy, 0.0f); }
    float2 o; o.x = vx; o.y = vy;
    ((float2*)out)[cbase] = o;
}

template<bool RELU>
__global__ __launch_bounds__(256) void agg64_kernel(
        const float* __restrict__ h, const int* __restrict__ offsets,
        const int* __restrict__ csr_src, const float* __restrict__ dinv,
        const float* __restrict__ bias, float* __restrict__ out, int n) {
    int lane = threadIdx.x & 63;
    int c = (blockIdx.x << 2) + (threadIdx.x >> 6);
    if (c >= n) return;
    size_t cbase = (size_t)c * 64 + lane;
    float acc = h[cbase];   // self loop
    int s = offsets[c], e = offsets[c + 1];
    int i = s;
    for (; i + 3 < e; i += 4) {
        int s0 = csr_src[i], s1 = csr_src[i+1], s2 = csr_src[i+2], s3 = csr_src[i+3];
        float a0 = h[(size_t)s0 * 64 + lane];
        float a1 = h[(size_t)s1 * 64 + lane];
        float a2 = h[(size_t)s2 * 64 + lane];
        float a3 = h[(size_t)s3 * 64 + lane];
        acc += a0 + a1; acc += a2 + a3;
    }
    for (; i < e; ++i) acc += h[(size_t)csr_src[i] * 64 + lane];
    float v = fmaf(acc, dinv[c], bias[lane]);
    if (RELU) v = fmaxf(v, 0.0f);
    out[cbase] = v;
}

// ---------------------------------------------------------------------------

extern "C" void kernel_launch(void* const* d_in, const int* in_sizes, int n_in,
                              void* d_out, int out_size, void* d_ws, size_t ws_size,
                              hipStream_t stream) {
    const float* x  = (const float*)d_in[0];
    const int*   ei = (const int*)  d_in[1];
    const float* W1 = (const float*)d_in[2];
    const float* b1 = (const float*)d_in[3];
    const float* W2 = (const float*)d_in[4];
    const float* b2 = (const float*)d_in[5];
    const float* W3 = (const float*)d_in[6];
    const float* b3 = (const float*)d_in[7];
    const float* W4 = (const float*)d_in[8];
    const float* b4 = (const float*)d_in[9];

    const int N = N_NODES, E = N_EDGES;
    const int NB = (N + 1023) / 1024;   // 49 scan blocks

    char* p = (char*)d_ws;
    auto carve = [&](size_t bytes) {
        char* q = p;
        p += (bytes + 255) & ~(size_t)255;
        return (void*)q;
    };
    int*   deg      = (int*)  carve((size_t)N * 4);
    int*   offsets  = (int*)  carve((size_t)(N + 1) * 4);
    int*   cursor   = (int*)  carve((size_t)N * 4);
    int*   csr_src  = (int*)  carve((size_t)E * 4);
    float* dinv     = (float*)carve((size_t)N * 4);
    int*   blocksum = (int*)  carve((size_t)NB * 4);
    int*   blockoff = (int*)  carve((size_t)NB * 4);
    float* A        = (float*)carve((size_t)N * 128 * 4);
    float* B        = (float*)carve((size_t)N * 128 * 4);

    // ---- graph build ----
    hipMemsetAsync(deg, 0, (size_t)N * 4, stream);
    count_kernel<<<(E + 255) / 256, 256, 0, stream>>>(ei, deg, E);
    dinv_kernel<<<(N + 255) / 256, 256, 0, stream>>>(deg, dinv, N);
    scan_blocksum<<<NB, 256, 0, stream>>>(deg, blocksum, N);
    scan_blockoff<<<1, 64, 0, stream>>>(blocksum, blockoff, NB, offsets, N, E);
    scan_fill<<<NB, 256, 0, stream>>>(deg, blockoff, offsets, cursor, N);
    fill_kernel<<<(E + 255) / 256, 256, 0, stream>>>(ei, cursor, csr_src, E);

    // ---- layers ----
    const int gemm128_grid = (N + 127) / 128;
    const int gemm64_grid  = (N + 255) / 256;
    const int agg_grid     = (N + 3) / 4;

    gemm_scale_kernel<128><<<gemm128_grid, 256, 0, stream>>>(x, W1, dinv, A, N);
    agg128_kernel<true><<<agg_grid, 256, 0, stream>>>(A, offsets, csr_src, dinv, b1, B, N);
    gemm_scale_kernel<128><<<gemm128_grid, 256, 0, stream>>>(B, W2, dinv, A, N);
    agg128_kernel<true><<<agg_grid, 256, 0, stream>>>(A, offsets, csr_src, dinv, b2, B, N);
    gemm_scale_kernel<128><<<gemm128_grid, 256, 0, stream>>>(B, W3, dinv, A, N);
    agg128_kernel<true><<<agg_grid, 256, 0, stream>>>(A, offsets, csr_src, dinv, b3, B, N);
    gemm_scale_kernel<64><<<gemm64_grid, 256, 0, stream>>>(B, W4, dinv, A, N);
    agg64_kernel<false><<<agg_grid, 256, 0, stream>>>(A, offsets, csr_src, dinv, b4, (float*)d_out, N);
}

// Round 3
// 526.593 us; speedup vs baseline: 1.2476x; 1.1025x over previous
//
#include <hip/hip_runtime.h>

#define N_NODES 50000
#define N_EDGES 800000
#define WIN_BITS 9
#define WIN 512                      // dests per bucket window
#define NBUK ((N_NODES + WIN - 1) / WIN)   // 98
#define BCAP 16384                   // arena entries per bucket (mean ~8163)

// ---------------------------------------------------------------------------
// P0: bucket edges by destination window. Packed entry: (src << 9) | (dst & 511)
// ---------------------------------------------------------------------------
__global__ __launch_bounds__(256) void p0_bucket(const int* __restrict__ ei,
                                                 int* __restrict__ gcur,
                                                 unsigned* __restrict__ arena, int E) {
    __shared__ int lcnt[NBUK];
    __shared__ int lbase[NBUK];
    int tid = threadIdx.x;
    int chunk = (E + gridDim.x - 1) / gridDim.x;
    int e0 = blockIdx.x * chunk;
    int e1 = e0 + chunk; if (e1 > E) e1 = E;
    for (int b = tid; b < NBUK; b += 256) lcnt[b] = 0;
    __syncthreads();
    for (int e = e0 + tid; e < e1; e += 256) {
        int dst = ei[E + e];
        atomicAdd(&lcnt[dst >> WIN_BITS], 1);
    }
    __syncthreads();
    for (int b = tid; b < NBUK; b += 256) {
        lbase[b] = atomicAdd(&gcur[b], lcnt[b]);
        lcnt[b] = 0;
    }
    __syncthreads();
    for (int e = e0 + tid; e < e1; e += 256) {
        int dst = ei[E + e];
        int src = ei[e];
        int b = dst >> WIN_BITS;
        int pos = lbase[b] + atomicAdd(&lcnt[b], 1);
        if (pos < BCAP)
            arena[(size_t)b * BCAP + pos] = ((unsigned)src << WIN_BITS) | (unsigned)(dst & (WIN - 1));
    }
}

// ---------------------------------------------------------------------------
// P1: per-bucket degree count (LDS histogram) + dinv. Coalesced window writes.
// ---------------------------------------------------------------------------
__global__ __launch_bounds__(256) void p1_count(const unsigned* __restrict__ arena,
                                                const int* __restrict__ gcur,
                                                int* __restrict__ deg,
                                                float* __restrict__ dinv, int n) {
    __shared__ int cnt[WIN];
    int b = blockIdx.x, tid = threadIdx.x;
    for (int j = tid; j < WIN; j += 256) cnt[j] = 0;
    __syncthreads();
    int m = gcur[b]; if (m > BCAP) m = BCAP;
    const unsigned* a = arena + (size_t)b * BCAP;
    for (int i = tid; i < m; i += 256) atomicAdd(&cnt[a[i] & (WIN - 1)], 1);
    __syncthreads();
    int base = b << WIN_BITS;
    for (int j = tid; j < WIN; j += 256) {
        int d = base + j;
        if (d < n) {
            int c = cnt[j];
            deg[d] = c;
            dinv[d] = rsqrtf((float)(c + 1));
        }
    }
}

// ---------------------------------------------------------------------------
// Scan (3-phase, unchanged)
// ---------------------------------------------------------------------------
__global__ __launch_bounds__(256) void scan_blocksum(const int* __restrict__ deg,
                                                     int* __restrict__ blocksum, int n) {
    int tid = threadIdx.x;
    int i0 = blockIdx.x * 1024 + tid * 4;
    int4 d = make_int4(0, 0, 0, 0);
    if (i0 + 3 < n) d = *(const int4*)&deg[i0];
    else {
        if (i0 < n)     d.x = deg[i0];
        if (i0 + 1 < n) d.y = deg[i0 + 1];
        if (i0 + 2 < n) d.z = deg[i0 + 2];
        if (i0 + 3 < n) d.w = deg[i0 + 3];
    }
    int s = d.x + d.y + d.z + d.w;
    #pragma unroll
    for (int off = 1; off < 64; off <<= 1) s += __shfl_xor(s, off);
    __shared__ int ws[4];
    if ((tid & 63) == 0) ws[tid >> 6] = s;
    __syncthreads();
    if (tid == 0) blocksum[blockIdx.x] = ws[0] + ws[1] + ws[2] + ws[3];
}

__global__ void scan_blockoff(const int* __restrict__ blocksum, int* __restrict__ blockoff,
                              int nb, int* __restrict__ offsets, int n, int total) {
    int lane = threadIdx.x;
    int v = (lane < nb) ? blocksum[lane] : 0;
    int orig = v;
    #pragma unroll
    for (int off = 1; off < 64; off <<= 1) {
        int t = __shfl_up(v, off);
        if (lane >= off) v += t;
    }
    if (lane < nb) blockoff[lane] = v - orig;
    if (lane == 0) offsets[n] = total;
}

__global__ __launch_bounds__(256) void scan_fill(const int* __restrict__ deg,
                                                 const int* __restrict__ blockoff,
                                                 int* __restrict__ offsets, int n) {
    int tid = threadIdx.x;
    int i0 = blockIdx.x * 1024 + tid * 4;
    int4 d = make_int4(0, 0, 0, 0);
    if (i0 + 3 < n) d = *(const int4*)&deg[i0];
    else {
        if (i0 < n)     d.x = deg[i0];
        if (i0 + 1 < n) d.y = deg[i0 + 1];
        if (i0 + 2 < n) d.z = deg[i0 + 2];
        if (i0 + 3 < n) d.w = deg[i0 + 3];
    }
    int ts = d.x + d.y + d.z + d.w;
    __shared__ int sbuf[256];
    sbuf[tid] = ts;
    __syncthreads();
    #pragma unroll
    for (int off = 1; off < 256; off <<= 1) {
        int t = (tid >= off) ? sbuf[tid - off] : 0;
        __syncthreads();
        sbuf[tid] += t;
        __syncthreads();
    }
    int base = blockoff[blockIdx.x] + (sbuf[tid] - ts);
    int o0 = base, o1 = o0 + d.x, o2 = o1 + d.y, o3 = o2 + d.z;
    if (i0 + 3 < n) {
        *(int4*)&offsets[i0] = make_int4(o0, o1, o2, o3);
    } else {
        if (i0 < n)     offsets[i0]     = o0;
        if (i0 + 1 < n) offsets[i0 + 1] = o1;
        if (i0 + 2 < n) offsets[i0 + 2] = o2;
    }
}

// ---------------------------------------------------------------------------
// P2: per-bucket CSR fill. LDS cursors; stores land in a ~32KB hot window.
// ---------------------------------------------------------------------------
__global__ __launch_bounds__(256) void p2_fill(const unsigned* __restrict__ arena,
                                               const int* __restrict__ gcur,
                                               const int* __restrict__ offsets,
                                               int* __restrict__ csr_src, int n) {
    __shared__ int cur[WIN];
    int b = blockIdx.x, tid = threadIdx.x;
    int base = b << WIN_BITS;
    for (int j = tid; j < WIN; j += 256) {
        int d = base + j;
        cur[j] = (d < n) ? offsets[d] : 0;
    }
    __syncthreads();
    int m = gcur[b]; if (m > BCAP) m = BCAP;
    const unsigned* a = arena + (size_t)b * BCAP;
    for (int i = tid; i < m; i += 256) {
        unsigned e = a[i];
        int pos = atomicAdd(&cur[e & (WIN - 1)], 1);
        csr_src[pos] = (int)(e >> WIN_BITS);
    }
}

// ---------------------------------------------------------------------------
// GEMM: h[i][j] = (x[i,:] @ W[:,j]) * dinv[i].   FI = 128 always.
// ---------------------------------------------------------------------------
template<int FO>
__global__ __launch_bounds__(256) void gemm_scale_kernel(
        const float* __restrict__ x, const float* __restrict__ W,
        const float* __restrict__ dinv, float* __restrict__ h, int n) {
    constexpr int TC   = FO / 16;
    constexpr int TR   = 256 / TC;
    constexpr int ROWS = TR * 4;

    __shared__ float w_lds[128 * FO];
    int tid = threadIdx.x;
    #pragma unroll 4
    for (int idx = tid * 4; idx < 128 * FO; idx += 1024)
        *(float4*)&w_lds[idx] = *(const float4*)&W[idx];
    __syncthreads();

    int tc = tid % TC, tr = tid / TC;
    int j0   = tc * 16;
    int row0 = blockIdx.x * ROWS + tr * 4;

    float acc[4][16];
    #pragma unroll
    for (int r = 0; r < 4; ++r)
        #pragma unroll
        for (int c = 0; c < 16; ++c) acc[r][c] = 0.0f;

    for (int kk = 0; kk < 128; kk += 4) {
        float xbuf[4][4];
        #pragma unroll
        for (int r = 0; r < 4; ++r) {
            int row = row0 + r;
            float4 v;
            if (row < n) v = *(const float4*)&x[(size_t)row * 128 + kk];
            else         v = make_float4(0.f, 0.f, 0.f, 0.f);
            xbuf[r][0] = v.x; xbuf[r][1] = v.y; xbuf[r][2] = v.z; xbuf[r][3] = v.w;
        }
        #pragma unroll
        for (int dk = 0; dk < 4; ++dk) {
            const float* wr = &w_lds[(kk + dk) * FO + j0];
            float w[16];
            #pragma unroll
            for (int q = 0; q < 4; ++q) {
                float4 wv = *(const float4*)&wr[q * 4];
                w[q*4+0] = wv.x; w[q*4+1] = wv.y; w[q*4+2] = wv.z; w[q*4+3] = wv.w;
            }
            #pragma unroll
            for (int r = 0; r < 4; ++r) {
                float xs = xbuf[r][dk];
                #pragma unroll
                for (int c = 0; c < 16; ++c)
                    acc[r][c] = fmaf(xs, w[c], acc[r][c]);
            }
        }
    }

    #pragma unroll
    for (int r = 0; r < 4; ++r) {
        int row = row0 + r;
        if (row < n) {
            float d = dinv[row];
            #pragma unroll
            for (int q = 0; q < 4; ++q) {
                float4 o;
                o.x = acc[r][q*4+0] * d;
                o.y = acc[r][q*4+1] * d;
                o.z = acc[r][q*4+2] * d;
                o.w = acc[r][q*4+3] * d;
                *(float4*)&h[(size_t)row * FO + j0 + q * 4] = o;
            }
        }
    }
}

// ---------------------------------------------------------------------------
// Aggregation: out[c][j] = dinv[c] * (h[c][j] + sum_{src in in(c)} h[src][j]) + b[j]
// One 64-lane wave per node; 4 nodes per 256-thread block.
// ---------------------------------------------------------------------------
template<bool RELU>
__global__ __launch_bounds__(256) void agg128_kernel(
        const float* __restrict__ h, const int* __restrict__ offsets,
        const int* __restrict__ csr_src, const float* __restrict__ dinv,
        const float* __restrict__ bias, float* __restrict__ out, int n) {
    int lane = threadIdx.x & 63;
    int c = (blockIdx.x << 2) + (threadIdx.x >> 6);
    if (c >= n) return;
    const float2* h2 = (const float2*)h;
    size_t cbase = (size_t)c * 64 + lane;
    float2 acc = h2[cbase];   // self loop (already scaled by dinv[c])
    int s = offsets[c], e = offsets[c + 1];
    int i = s;
    for (; i + 3 < e; i += 4) {
        int s0 = csr_src[i], s1 = csr_src[i+1], s2 = csr_src[i+2], s3 = csr_src[i+3];
        float2 a0 = h2[(size_t)s0 * 64 + lane];
        float2 a1 = h2[(size_t)s1 * 64 + lane];
        float2 a2 = h2[(size_t)s2 * 64 + lane];
        float2 a3 = h2[(size_t)s3 * 64 + lane];
        acc.x += a0.x + a1.x; acc.y += a0.y + a1.y;
        acc.x += a2.x + a3.x; acc.y += a2.y + a3.y;
    }
    for (; i < e; ++i) {
        float2 a = h2[(size_t)csr_src[i] * 64 + lane];
        acc.x += a.x; acc.y += a.y;
    }
    float dc = dinv[c];
    float2 bb = ((const float2*)bias)[lane];
    float vx = fmaf(acc.x, dc, bb.x);
    float vy = fmaf(acc.y, dc, bb.y);
    if (RELU) { vx = fmaxf(vx, 0.0f); vy = fmaxf(vy, 0.0f); }
    float2 o; o.x = vx; o.y = vy;
    ((float2*)out)[cbase] = o;
}

template<bool RELU>
__global__ __launch_bounds__(256) void agg64_kernel(
        const float* __restrict__ h, const int* __restrict__ offsets,
        const int* __restrict__ csr_src, const float* __restrict__ dinv,
        const float* __restrict__ bias, float* __restrict__ out, int n) {
    int lane = threadIdx.x & 63;
    int c = (blockIdx.x << 2) + (threadIdx.x >> 6);
    if (c >= n) return;
    size_t cbase = (size_t)c * 64 + lane;
    float acc = h[cbase];
    int s = offsets[c], e = offsets[c + 1];
    int i = s;
    for (; i + 3 < e; i += 4) {
        int s0 = csr_src[i], s1 = csr_src[i+1], s2 = csr_src[i+2], s3 = csr_src[i+3];
        float a0 = h[(size_t)s0 * 64 + lane];
        float a1 = h[(size_t)s1 * 64 + lane];
        float a2 = h[(size_t)s2 * 64 + lane];
        float a3 = h[(size_t)s3 * 64 + lane];
        acc += a0 + a1; acc += a2 + a3;
    }
    for (; i < e; ++i) acc += h[(size_t)csr_src[i] * 64 + lane];
    float v = fmaf(acc, dinv[c], bias[lane]);
    if (RELU) v = fmaxf(v, 0.0f);
    out[cbase] = v;
}

// ---------------------------------------------------------------------------

extern "C" void kernel_launch(void* const* d_in, const int* in_sizes, int n_in,
                              void* d_out, int out_size, void* d_ws, size_t ws_size,
                              hipStream_t stream) {
    const float* x  = (const float*)d_in[0];
    const int*   ei = (const int*)  d_in[1];
    const float* W1 = (const float*)d_in[2];
    const float* b1 = (const float*)d_in[3];
    const float* W2 = (const float*)d_in[4];
    const float* b2 = (const float*)d_in[5];
    const float* W3 = (const float*)d_in[6];
    const float* b3 = (const float*)d_in[7];
    const float* W4 = (const float*)d_in[8];
    const float* b4 = (const float*)d_in[9];

    const int N = N_NODES, E = N_EDGES;
    const int NSB = (N + 1023) / 1024;   // scan blocks

    char* p = (char*)d_ws;
    auto carve = [&](size_t bytes) {
        char* q = p;
        p += (bytes + 255) & ~(size_t)255;
        return (void*)q;
    };
    int*      deg      = (int*)     carve((size_t)N * 4);
    int*      offsets  = (int*)     carve((size_t)(N + 1) * 4);
    int*      csr_src  = (int*)     carve((size_t)E * 4);
    float*    dinv     = (float*)   carve((size_t)N * 4);
    int*      blocksum = (int*)     carve((size_t)NSB * 4);
    int*      blockoff = (int*)     carve((size_t)NSB * 4);
    int*      gcur     = (int*)     carve((size_t)NBUK * 4);
    unsigned* arena    = (unsigned*)carve((size_t)NBUK * BCAP * 4);   // 6.4 MB
    float*    A        = (float*)   carve((size_t)N * 128 * 4);
    float*    B        = (float*)   carve((size_t)N * 128 * 4);

    // ---- graph build ----
    hipMemsetAsync(gcur, 0, (size_t)NBUK * 4, stream);
    p0_bucket<<<256, 256, 0, stream>>>(ei, gcur, arena, E);
    p1_count<<<NBUK, 256, 0, stream>>>(arena, gcur, deg, dinv, N);
    scan_blocksum<<<NSB, 256, 0, stream>>>(deg, blocksum, N);
    scan_blockoff<<<1, 64, 0, stream>>>(blocksum, blockoff, NSB, offsets, N, E);
    scan_fill<<<NSB, 256, 0, stream>>>(deg, blockoff, offsets, N);
    p2_fill<<<NBUK, 256, 0, stream>>>(arena, gcur, offsets, csr_src, N);

    // ---- layers ----
    const int gemm128_grid = (N + 127) / 128;
    const int gemm64_grid  = (N + 255) / 256;
    const int agg_grid     = (N + 3) / 4;

    gemm_scale_kernel<128><<<gemm128_grid, 256, 0, stream>>>(x, W1, dinv, A, N);
    agg128_kernel<true><<<agg_grid, 256, 0, stream>>>(A, offsets, csr_src, dinv, b1, B, N);
    gemm_scale_kernel<128><<<gemm128_grid, 256, 0, stream>>>(B, W2, dinv, A, N);
    agg128_kernel<true><<<agg_grid, 256, 0, stream>>>(A, offsets, csr_src, dinv, b2, B, N);
    gemm_scale_kernel<128><<<gemm128_grid, 256, 0, stream>>>(B, W3, dinv, A, N);
    agg128_kernel<true><<<agg_grid, 256, 0, stream>>>(A, offsets, csr_src, dinv, b3, B, N);
    gemm_scale_kernel<64><<<gemm64_grid, 256, 0, stream>>>(B, W4, dinv, A, N);
    agg64_kernel<false><<<agg_grid, 256, 0, stream>>>(A, offsets, csr_src, dinv, b4, (float*)d_out, N);
}

// Round 4
// 376.004 us; speedup vs baseline: 1.7473x; 1.4005x over previous
//
#include <hip/hip_runtime.h>
#include <hip/hip_fp16.h>

#define N_NODES 50000
#define N_EDGES 800000
#define WIN_BITS 9
#define WIN 512
#define NBUK ((N_NODES + WIN - 1) / WIN)   // 98
#define BCAP 16384

// ---------------------------------------------------------------------------
// P0: bucket edges by destination window. Packed entry: (src << 9) | (dst & 511)
// ---------------------------------------------------------------------------
__global__ __launch_bounds__(256) void p0_bucket(const int* __restrict__ ei,
                                                 int* __restrict__ gcur,
                                                 unsigned* __restrict__ arena, int E) {
    __shared__ int lcnt[NBUK];
    __shared__ int lbase[NBUK];
    int tid = threadIdx.x;
    int chunk = (E + gridDim.x - 1) / gridDim.x;
    int e0 = blockIdx.x * chunk;
    int e1 = e0 + chunk; if (e1 > E) e1 = E;
    for (int b = tid; b < NBUK; b += 256) lcnt[b] = 0;
    __syncthreads();
    for (int e = e0 + tid; e < e1; e += 256) {
        int dst = ei[E + e];
        atomicAdd(&lcnt[dst >> WIN_BITS], 1);
    }
    __syncthreads();
    for (int b = tid; b < NBUK; b += 256) {
        lbase[b] = atomicAdd(&gcur[b], lcnt[b]);
        lcnt[b] = 0;
    }
    __syncthreads();
    for (int e = e0 + tid; e < e1; e += 256) {
        int dst = ei[E + e];
        int src = ei[e];
        int b = dst >> WIN_BITS;
        int pos = lbase[b] + atomicAdd(&lcnt[b], 1);
        if (pos < BCAP)
            arena[(size_t)b * BCAP + pos] = ((unsigned)src << WIN_BITS) | (unsigned)(dst & (WIN - 1));
    }
}

// ---------------------------------------------------------------------------
// P1: per-bucket degree count (LDS histogram) + dinv.
// ---------------------------------------------------------------------------
__global__ __launch_bounds__(256) void p1_count(const unsigned* __restrict__ arena,
                                                const int* __restrict__ gcur,
                                                int* __restrict__ deg,
                                                float* __restrict__ dinv, int n) {
    __shared__ int cnt[WIN];
    int b = blockIdx.x, tid = threadIdx.x;
    for (int j = tid; j < WIN; j += 256) cnt[j] = 0;
    __syncthreads();
    int m = gcur[b]; if (m > BCAP) m = BCAP;
    const unsigned* a = arena + (size_t)b * BCAP;
    for (int i = tid; i < m; i += 256) atomicAdd(&cnt[a[i] & (WIN - 1)], 1);
    __syncthreads();
    int base = b << WIN_BITS;
    for (int j = tid; j < WIN; j += 256) {
        int d = base + j;
        if (d < n) {
            int c = cnt[j];
            deg[d] = c;
            dinv[d] = rsqrtf((float)(c + 1));
        }
    }
}

// ---------------------------------------------------------------------------
// Scan (3-phase)
// ---------------------------------------------------------------------------
__global__ __launch_bounds__(256) void scan_blocksum(const int* __restrict__ deg,
                                                     int* __restrict__ blocksum, int n) {
    int tid = threadIdx.x;
    int i0 = blockIdx.x * 1024 + tid * 4;
    int4 d = make_int4(0, 0, 0, 0);
    if (i0 + 3 < n) d = *(const int4*)&deg[i0];
    else {
        if (i0 < n)     d.x = deg[i0];
        if (i0 + 1 < n) d.y = deg[i0 + 1];
        if (i0 + 2 < n) d.z = deg[i0 + 2];
        if (i0 + 3 < n) d.w = deg[i0 + 3];
    }
    int s = d.x + d.y + d.z + d.w;
    #pragma unroll
    for (int off = 1; off < 64; off <<= 1) s += __shfl_xor(s, off);
    __shared__ int ws[4];
    if ((tid & 63) == 0) ws[tid >> 6] = s;
    __syncthreads();
    if (tid == 0) blocksum[blockIdx.x] = ws[0] + ws[1] + ws[2] + ws[3];
}

__global__ void scan_blockoff(const int* __restrict__ blocksum, int* __restrict__ blockoff,
                              int nb, int* __restrict__ offsets, int n, int total) {
    int lane = threadIdx.x;
    int v = (lane < nb) ? blocksum[lane] : 0;
    int orig = v;
    #pragma unroll
    for (int off = 1; off < 64; off <<= 1) {
        int t = __shfl_up(v, off);
        if (lane >= off) v += t;
    }
    if (lane < nb) blockoff[lane] = v - orig;
    if (lane == 0) offsets[n] = total;
}

__global__ __launch_bounds__(256) void scan_fill(const int* __restrict__ deg,
                                                 const int* __restrict__ blockoff,
                                                 int* __restrict__ offsets, int n) {
    int tid = threadIdx.x;
    int i0 = blockIdx.x * 1024 + tid * 4;
    int4 d = make_int4(0, 0, 0, 0);
    if (i0 + 3 < n) d = *(const int4*)&deg[i0];
    else {
        if (i0 < n)     d.x = deg[i0];
        if (i0 + 1 < n) d.y = deg[i0 + 1];
        if (i0 + 2 < n) d.z = deg[i0 + 2];
        if (i0 + 3 < n) d.w = deg[i0 + 3];
    }
    int ts = d.x + d.y + d.z + d.w;
    __shared__ int sbuf[256];
    sbuf[tid] = ts;
    __syncthreads();
    #pragma unroll
    for (int off = 1; off < 256; off <<= 1) {
        int t = (tid >= off) ? sbuf[tid - off] : 0;
        __syncthreads();
        sbuf[tid] += t;
        __syncthreads();
    }
    int base = blockoff[blockIdx.x] + (sbuf[tid] - ts);
    int o0 = base, o1 = o0 + d.x, o2 = o1 + d.y, o3 = o2 + d.z;
    if (i0 + 3 < n) {
        *(int4*)&offsets[i0] = make_int4(o0, o1, o2, o3);
    } else {
        if (i0 < n)     offsets[i0]     = o0;
        if (i0 + 1 < n) offsets[i0 + 1] = o1;
        if (i0 + 2 < n) offsets[i0 + 2] = o2;
    }
}

// ---------------------------------------------------------------------------
// P2: per-bucket CSR fill.
// ---------------------------------------------------------------------------
__global__ __launch_bounds__(256) void p2_fill(const unsigned* __restrict__ arena,
                                               const int* __restrict__ gcur,
                                               const int* __restrict__ offsets,
                                               int* __restrict__ csr_src, int n) {
    __shared__ int cur[WIN];
    int b = blockIdx.x, tid = threadIdx.x;
    int base = b << WIN_BITS;
    for (int j = tid; j < WIN; j += 256) {
        int d = base + j;
        cur[j] = (d < n) ? offsets[d] : 0;
    }
    __syncthreads();
    int m = gcur[b]; if (m > BCAP) m = BCAP;
    const unsigned* a = arena + (size_t)b * BCAP;
    for (int i = tid; i < m; i += 256) {
        unsigned e = a[i];
        int pos = atomicAdd(&cur[e & (WIN - 1)], 1);
        csr_src[pos] = (int)(e >> WIN_BITS);
    }
}

// ---------------------------------------------------------------------------
// GEMM: h[i][j] = fp16( (x[i,:] @ W[:,j]) * dinv[i] ).  FI = 128.
// 128 rows/block. LDS W tile stored bank-swizzled: thread tc's quad q lives
// at float4-slot q*TC+tc of each row -> ds_read_b128 covers all 32 banks.
// x double-buffered in registers (prefetch 1 K-step = 4 floats/row ahead).
// ---------------------------------------------------------------------------
template<int FO>
__global__ __launch_bounds__(FO * 2) void gemm_scale_kernel(
        const float* __restrict__ x, const float* __restrict__ W,
        const float* __restrict__ dinv, __half* __restrict__ h, int n) {
    constexpr int TC      = FO / 16;     // 8 (FO=128) or 4 (FO=64)
    constexpr int THREADS = TC * 32;     // 256 or 128
    constexpr int F4      = FO / 4;      // float4s per W row

    __shared__ float w_lds[128 * FO];
    int tid = threadIdx.x;
    // stage W with swizzle: src float4 jf4 = tcg*4+qg  ->  dst slot qg*TC+tcg
    for (int i = tid; i < 128 * F4; i += THREADS) {
        int r = i / F4, jf4 = i % F4;
        int tcg = jf4 >> 2, qg = jf4 & 3;
        float4 v = *(const float4*)&W[(size_t)r * FO + jf4 * 4];
        *(float4*)&w_lds[(size_t)r * FO + (qg * TC + tcg) * 4] = v;
    }
    __syncthreads();

    int tc = tid % TC, tr = tid / TC;    // tr in 0..31
    int j0 = tc * 16;
    int row0 = blockIdx.x * 128 + tr * 4;

    const float* xp[4];
    #pragma unroll
    for (int r = 0; r < 4; ++r) {
        int rowc = row0 + r; if (rowc > n - 1) rowc = n - 1;   // clamp: safe reads
        xp[r] = x + (size_t)rowc * 128;
    }

    float acc[4][16];
    #pragma unroll
    for (int r = 0; r < 4; ++r)
        #pragma unroll
        for (int c = 0; c < 16; ++c) acc[r][c] = 0.0f;

    float4 xb0[4], xb1[4];
    #pragma unroll
    for (int r = 0; r < 4; ++r) xb0[r] = *(const float4*)&xp[r][0];

    auto compute = [&](const float4* xb, int kk) {
        #pragma unroll
        for (int dk = 0; dk < 4; ++dk) {
            float w[16];
            #pragma unroll
            for (int q = 0; q < 4; ++q)
                *(float4*)&w[q * 4] = *(const float4*)&w_lds[(size_t)(kk + dk) * FO + (q * TC + tc) * 4];
            #pragma unroll
            for (int r = 0; r < 4; ++r) {
                float xs = (&xb[r].x)[dk];
                #pragma unroll
                for (int c = 0; c < 16; ++c)
                    acc[r][c] = fmaf(xs, w[c], acc[r][c]);
            }
        }
    };

    for (int kk = 0; kk < 128; kk += 8) {
        #pragma unroll
        for (int r = 0; r < 4; ++r) xb1[r] = *(const float4*)&xp[r][kk + 4];
        compute(xb0, kk);
        if (kk + 8 < 128) {
            #pragma unroll
            for (int r = 0; r < 4; ++r) xb0[r] = *(const float4*)&xp[r][kk + 8];
        }
        compute(xb1, kk + 4);
    }

    #pragma unroll
    for (int r = 0; r < 4; ++r) {
        int row = row0 + r;
        if (row < n) {
            float d = dinv[row];
            __half2 hv[8];
            #pragma unroll
            for (int q = 0; q < 8; ++q)
                hv[q] = __float22half2_rn(make_float2(acc[r][2 * q] * d, acc[r][2 * q + 1] * d));
            uint4* dst = (uint4*)&h[(size_t)row * FO + j0];
            const uint4* srcp = (const uint4*)hv;
            dst[0] = srcp[0];
            dst[1] = srcp[1];
        }
    }
}

// ---------------------------------------------------------------------------
// Aggregation: out[c] = dinv[c]*(h[c] + sum_{src} h[src]) + b, fp16 gathers,
// fp32 accumulate. One wave per node; node index scalarized -> s_load indices.
// ---------------------------------------------------------------------------
template<bool RELU>
__global__ __launch_bounds__(256) void agg128_kernel(
        const __half2* __restrict__ h2, const int* __restrict__ offsets,
        const int* __restrict__ csr_src, const float* __restrict__ dinv,
        const float* __restrict__ bias, float* __restrict__ out, int n) {
    int lane = threadIdx.x & 63;
    int c = (blockIdx.x << 2) + (threadIdx.x >> 6);
    if (c >= n) return;
    c = __builtin_amdgcn_readfirstlane(c);
    float2 acc = __half22float2(h2[(size_t)c * 64 + lane]);   // self loop
    int s = offsets[c], e = offsets[c + 1];
    int i = s;
    for (; i + 3 < e; i += 4) {
        int s0 = csr_src[i], s1 = csr_src[i + 1], s2 = csr_src[i + 2], s3 = csr_src[i + 3];
        float2 f0 = __half22float2(h2[(size_t)s0 * 64 + lane]);
        float2 f1 = __half22float2(h2[(size_t)s1 * 64 + lane]);
        float2 f2 = __half22float2(h2[(size_t)s2 * 64 + lane]);
        float2 f3 = __half22float2(h2[(size_t)s3 * 64 + lane]);
        acc.x += f0.x + f1.x; acc.y += f0.y + f1.y;
        acc.x += f2.x + f3.x; acc.y += f2.y + f3.y;
    }
    for (; i < e; ++i) {
        float2 f = __half22float2(h2[(size_t)csr_src[i] * 64 + lane]);
        acc.x += f.x; acc.y += f.y;
    }
    float dc = dinv[c];
    float2 bb = ((const float2*)bias)[lane];
    float vx = fmaf(acc.x, dc, bb.x);
    float vy = fmaf(acc.y, dc, bb.y);
    if (RELU) { vx = fmaxf(vx, 0.0f); vy = fmaxf(vy, 0.0f); }
    float2 o; o.x = vx; o.y = vy;
    ((float2*)out)[(size_t)c * 64 + lane] = o;
}

template<bool RELU>
__global__ __launch_bounds__(256) void agg64_kernel(
        const __half* __restrict__ hh, const int* __restrict__ offsets,
        const int* __restrict__ csr_src, const float* __restrict__ dinv,
        const float* __restrict__ bias, float* __restrict__ out, int n) {
    int lane = threadIdx.x & 63;
    int c = (blockIdx.x << 2) + (threadIdx.x >> 6);
    if (c >= n) return;
    c = __builtin_amdgcn_readfirstlane(c);
    float acc = __half2float(hh[(size_t)c * 64 + lane]);
    int s = offsets[c], e = offsets[c + 1];
    int i = s;
    for (; i + 3 < e; i += 4) {
        int s0 = csr_src[i], s1 = csr_src[i + 1], s2 = csr_src[i + 2], s3 = csr_src[i + 3];
        float a0 = __half2float(hh[(size_t)s0 * 64 + lane]);
        float a1 = __half2float(hh[(size_t)s1 * 64 + lane]);
        float a2 = __half2float(hh[(size_t)s2 * 64 + lane]);
        float a3 = __half2float(hh[(size_t)s3 * 64 + lane]);
        acc += a0 + a1; acc += a2 + a3;
    }
    for (; i < e; ++i) acc += __half2float(hh[(size_t)csr_src[i] * 64 + lane]);
    float v = fmaf(acc, dinv[c], bias[lane]);
    if (RELU) v = fmaxf(v, 0.0f);
    out[(size_t)c * 64 + lane] = v;
}

// ---------------------------------------------------------------------------

extern "C" void kernel_launch(void* const* d_in, const int* in_sizes, int n_in,
                              void* d_out, int out_size, void* d_ws, size_t ws_size,
                              hipStream_t stream) {
    const float* x  = (const float*)d_in[0];
    const int*   ei = (const int*)  d_in[1];
    const float* W1 = (const float*)d_in[2];
    const float* b1 = (const float*)d_in[3];
    const float* W2 = (const float*)d_in[4];
    const float* b2 = (const float*)d_in[5];
    const float* W3 = (const float*)d_in[6];
    const float* b3 = (const float*)d_in[7];
    const float* W4 = (const float*)d_in[8];
    const float* b4 = (const float*)d_in[9];

    const int N = N_NODES, E = N_EDGES;
    const int NSB = (N + 1023) / 1024;

    char* p = (char*)d_ws;
    auto carve = [&](size_t bytes) {
        char* q = p;
        p += (bytes + 255) & ~(size_t)255;
        return (void*)q;
    };
    int*      deg      = (int*)     carve((size_t)N * 4);
    int*      offsets  = (int*)     carve((size_t)(N + 1) * 4);
    int*      csr_src  = (int*)     carve((size_t)E * 4);
    float*    dinv     = (float*)   carve((size_t)N * 4);
    int*      blocksum = (int*)     carve((size_t)NSB * 4);
    int*      blockoff = (int*)     carve((size_t)NSB * 4);
    int*      gcur     = (int*)     carve((size_t)NBUK * 4);
    unsigned* arena    = (unsigned*)carve((size_t)NBUK * BCAP * 4);
    __half*   A        = (__half*)  carve((size_t)N * 128 * 2);   // fp16 GEMM out
    float*    B        = (float*)   carve((size_t)N * 128 * 4);   // fp32 agg out

    // ---- graph build ----
    hipMemsetAsync(gcur, 0, (size_t)NBUK * 4, stream);
    p0_bucket<<<256, 256, 0, stream>>>(ei, gcur, arena, E);
    p1_count<<<NBUK, 256, 0, stream>>>(arena, gcur, deg, dinv, N);
    scan_blocksum<<<NSB, 256, 0, stream>>>(deg, blocksum, N);
    scan_blockoff<<<1, 64, 0, stream>>>(blocksum, blockoff, NSB, offsets, N, E);
    scan_fill<<<NSB, 256, 0, stream>>>(deg, blockoff, offsets, N);
    p2_fill<<<NBUK, 256, 0, stream>>>(arena, gcur, offsets, csr_src, N);

    // ---- layers ----
    const int gemm_grid = (N + 127) / 128;   // 391
    const int agg_grid  = (N + 3) / 4;

    gemm_scale_kernel<128><<<gemm_grid, 256, 0, stream>>>(x, W1, dinv, A, N);
    agg128_kernel<true><<<agg_grid, 256, 0, stream>>>((const __half2*)A, offsets, csr_src, dinv, b1, B, N);
    gemm_scale_kernel<128><<<gemm_grid, 256, 0, stream>>>(B, W2, dinv, A, N);
    agg128_kernel<true><<<agg_grid, 256, 0, stream>>>((const __half2*)A, offsets, csr_src, dinv, b2, B, N);
    gemm_scale_kernel<128><<<gemm_grid, 256, 0, stream>>>(B, W3, dinv, A, N);
    agg128_kernel<true><<<agg_grid, 256, 0, stream>>>((const __half2*)A, offsets, csr_src, dinv, b3, B, N);
    gemm_scale_kernel<64><<<gemm_grid, 128, 0, stream>>>(B, W4, dinv, A, N);
    agg64_kernel<false><<<agg_grid, 256, 0, stream>>>(A, offsets, csr_src, dinv, b4, (float*)d_out, N);
}